// Round 1
// baseline (573.932 us; speedup 1.0000x reference)
//
#include <hip/hip_runtime.h>
#include <hip/hip_bf16.h>
#include <stdint.h>

// EncoderBlock on MI355X (gfx950), bf16 MFMA pipeline.
// B=4 S=2048 D=1024 H=16 DK=64 DFF=4096.  All matmuls as NT GEMM (A[M,K] x W[N,K]).
// ws layout (MB, 1<<20): xb[0,16) wqkvb[16,22) wob[22,24) w1b[24,32) w2b[32,40)
//   Q[40,56) K[56,72) V[72,88) ctx[88,104)
//   reuse: aout=[40,56) x1b=[56,72) hid=[88,152) ffb=[72,88).  Peak 152MB.

#define DI __device__ __forceinline__

typedef __attribute__((ext_vector_type(4))) float f32x4;
typedef __attribute__((ext_vector_type(8))) short bf16x8;
typedef __attribute__((ext_vector_type(4))) short s16x4;

#define B_ 4
#define S_ 2048
#define D_ 1024
#define H_ 16
#define DK_ 64
#define DFF_ 4096
#define M_ 8192

DI float bf2f(short s) {
  union { unsigned u; float f; } v;
  v.u = ((unsigned)(unsigned short)s) << 16;
  return v.f;
}
DI short f2bf(float f) {
  union { float f; unsigned u; } v;
  v.f = f;
  unsigned r = v.u + 0x7FFFu + ((v.u >> 16) & 1u);
  return (short)(r >> 16);
}

// ---------------- fp32 -> bf16 convert (vectorized) ----------------
__global__ __launch_bounds__(256) void cvt_kernel(const float* __restrict__ in,
                                                  short* __restrict__ out, int n) {
  long i = ((long)blockIdx.x * blockDim.x + threadIdx.x) * 8;
  if (i >= n) return;
  f32x4 a = *(const f32x4*)(in + i);
  f32x4 b = *(const f32x4*)(in + i + 4);
  bf16x8 r;
  r[0] = f2bf(a[0]); r[1] = f2bf(a[1]); r[2] = f2bf(a[2]); r[3] = f2bf(a[3]);
  r[4] = f2bf(b[0]); r[5] = f2bf(b[1]); r[6] = f2bf(b[2]); r[7] = f2bf(b[3]);
  *(bf16x8*)(out + i) = r;
}

// ---------------- GEMM C = A @ B^T (+bias, epilogue variants) ----------------
DI void gl_lds16(const void* g, void* l) {
  __builtin_amdgcn_global_load_lds(
      (const __attribute__((address_space(1))) unsigned int*)g,
      (__attribute__((address_space(3))) unsigned int*)l, 16, 0, 0);
}

// MODE 0: bf16 out + bias; MODE 1: + ReLU; MODE 2: QKV scatter to [B,H,S,DK]
template <int MODE>
__global__ __launch_bounds__(256, 2)
void gemm_bt(const short* __restrict__ A, const short* __restrict__ Bm,
             const float* __restrict__ bias0, const float* __restrict__ bias1,
             const float* __restrict__ bias2, short* __restrict__ C,
             int M, int N, int K,
             short* __restrict__ Qo, short* __restrict__ Ko, short* __restrict__ Vo) {
  __shared__ short As[128 * 32];
  __shared__ short Bs[128 * 32];
  const int t = threadIdx.x, w = t >> 6, l = t & 63;
  const int row0 = blockIdx.y * 128, col0 = blockIdx.x * 128;
  const int wr = (w >> 1) * 64, wc = (w & 1) * 64;
  const int lr = l & 15, lk = l >> 4;

  f32x4 acc[4][4] = {};

  // staging: 4096 bf16 per tile, 2x16B chunks per thread, linear LDS dest
  const int e0 = (w * 64 + l) * 8;
  const int e1 = ((4 + w) * 64 + l) * 8;
  const int ar0 = e0 >> 5, ac0 = e0 & 31;
  const int ar1 = e1 >> 5, ac1 = e1 & 31;
  short* la0 = &As[w * 512];
  short* la1 = &As[(4 + w) * 512];
  short* lb0 = &Bs[w * 512];
  short* lb1 = &Bs[(4 + w) * 512];
  const short* Ab = A + (long)row0 * K;
  const short* Bb = Bm + (long)col0 * K;

  for (int k0 = 0; k0 < K; k0 += 32) {
    __syncthreads();
    gl_lds16(Ab + (long)ar0 * K + k0 + ac0, la0);
    gl_lds16(Ab + (long)ar1 * K + k0 + ac1, la1);
    gl_lds16(Bb + (long)ar0 * K + k0 + ac0, lb0);
    gl_lds16(Bb + (long)ar1 * K + k0 + ac1, lb1);
    __syncthreads();
    bf16x8 af[4], bfr[4];
#pragma unroll
    for (int m = 0; m < 4; ++m)
      af[m] = *(const bf16x8*)&As[(wr + m * 16 + lr) * 32 + lk * 8];
#pragma unroll
    for (int n = 0; n < 4; ++n)
      bfr[n] = *(const bf16x8*)&Bs[(wc + n * 16 + lr) * 32 + lk * 8];
#pragma unroll
    for (int m = 0; m < 4; ++m)
#pragma unroll
      for (int n = 0; n < 4; ++n)
        acc[m][n] =
            __builtin_amdgcn_mfma_f32_16x16x32_bf16(af[m], bfr[n], acc[m][n], 0, 0, 0);
  }

  // epilogue: C/D layout col = lane&15, row = (lane>>4)*4 + j
#pragma unroll
  for (int m = 0; m < 4; ++m) {
#pragma unroll
    for (int n = 0; n < 4; ++n) {
#pragma unroll
      for (int j = 0; j < 4; ++j) {
        int r = row0 + wr + m * 16 + lk * 4 + j;
        int c = col0 + wc + n * 16 + lr;
        float v = acc[m][n][j];
        if (MODE == 2) {
          int which = c >> 10;
          int cc = c & 1023;
          v += (which == 0 ? bias0[cc] : which == 1 ? bias1[cc] : bias2[cc]);
          int h = cc >> 6, dk = cc & 63;
          int bb = r >> 11, s = r & 2047;
          short* dst = (which == 0 ? Qo : which == 1 ? Ko : Vo);
          dst[(((long)(bb * H_ + h) * S_) + s) * DK_ + dk] = f2bf(v);
        } else {
          v += bias0[c];
          if (MODE == 1) v = fmaxf(v, 0.0f);
          C[(long)r * N + c] = f2bf(v);
        }
      }
    }
  }
}

// ---------------- Flash attention (non-causal), QB=64 rows/block ----------------
__global__ __launch_bounds__(256, 2)
void attn_kernel(const short* __restrict__ Q, const short* __restrict__ K,
                 const short* __restrict__ V, short* __restrict__ ctx) {
  __shared__ short Ks[64 * 72];      // K tile [64 kv][64 dk] padded
  __shared__ short Vt[64 * 72];      // V^T tile [64 dk][64 kv] padded
  __shared__ short Pb[4][16 * 72];   // per-wave P [16 q][64 kv] padded

  const int t = threadIdx.x, w = t >> 6, l = t & 63;
  const int lr = l & 15, lk = l >> 4;
  const int qt = blockIdx.x;   // S/64 tiles
  const int bh = blockIdx.y;   // b*H + h
  const long base = (long)bh * S_ * DK_;
  const int s0 = qt * 64;

  // Q fragments for this wave's 16 rows (A-operand: row = lane&15)
  bf16x8 qf[2];
  {
    const short* qp = Q + base + (long)(s0 + w * 16 + lr) * DK_ + lk * 8;
    qf[0] = *(const bf16x8*)(qp);
    qf[1] = *(const bf16x8*)(qp + 32);
  }

  f32x4 o[4] = {};
  float mrow[4], lrow[4];
#pragma unroll
  for (int j = 0; j < 4; ++j) { mrow[j] = -1e30f; lrow[j] = 0.0f; }

  const int srow = t >> 2, sc0 = (t & 3) * 16;

  for (int k0 = 0; k0 < S_; k0 += 64) {
    __syncthreads();
    {
      const short* kp = K + base + (long)(k0 + srow) * DK_ + sc0;
      bf16x8 k0v = *(const bf16x8*)kp;
      bf16x8 k1v = *(const bf16x8*)(kp + 8);
      *(bf16x8*)&Ks[srow * 72 + sc0] = k0v;
      *(bf16x8*)&Ks[srow * 72 + sc0 + 8] = k1v;
      const short* vp = V + base + (long)(k0 + srow) * DK_ + sc0;
      bf16x8 v0v = *(const bf16x8*)vp;
      bf16x8 v1v = *(const bf16x8*)(vp + 8);
#pragma unroll
      for (int i = 0; i < 8; ++i) Vt[(sc0 + i) * 72 + srow] = v0v[i];
#pragma unroll
      for (int i = 0; i < 8; ++i) Vt[(sc0 + 8 + i) * 72 + srow] = v1v[i];
    }
    __syncthreads();

    // scores S = Q @ K^T  (4 col-tiles x 2 K-steps)
    f32x4 sacc[4] = {};
#pragma unroll
    for (int n = 0; n < 4; ++n) {
      bf16x8 kf0 = *(const bf16x8*)&Ks[(n * 16 + lr) * 72 + lk * 8];
      bf16x8 kf1 = *(const bf16x8*)&Ks[(n * 16 + lr) * 72 + 32 + lk * 8];
      sacc[n] = __builtin_amdgcn_mfma_f32_16x16x32_bf16(qf[0], kf0, sacc[n], 0, 0, 0);
      sacc[n] = __builtin_amdgcn_mfma_f32_16x16x32_bf16(qf[1], kf1, sacc[n], 0, 0, 0);
    }

    // online softmax; rows = lk*4+j, cols spread over lr (16 lanes) x 4 tiles
    float tmax[4];
#pragma unroll
    for (int j = 0; j < 4; ++j)
      tmax[j] = fmaxf(fmaxf(sacc[0][j], sacc[1][j]), fmaxf(sacc[2][j], sacc[3][j]));
#pragma unroll
    for (int mask = 1; mask < 16; mask <<= 1)
#pragma unroll
      for (int j = 0; j < 4; ++j) tmax[j] = fmaxf(tmax[j], __shfl_xor(tmax[j], mask, 64));

    float mnew[4], fac[4];
#pragma unroll
    for (int j = 0; j < 4; ++j) {
      mnew[j] = fmaxf(mrow[j], tmax[j] * 0.125f);
      fac[j] = __expf(mrow[j] - mnew[j]);
    }
    float psum[4] = {0.f, 0.f, 0.f, 0.f};
#pragma unroll
    for (int n = 0; n < 4; ++n)
#pragma unroll
      for (int j = 0; j < 4; ++j) {
        float p = __expf(sacc[n][j] * 0.125f - mnew[j]);
        psum[j] += p;
        Pb[w][(lk * 4 + j) * 72 + n * 16 + lr] = f2bf(p);
      }
#pragma unroll
    for (int mask = 1; mask < 16; mask <<= 1)
#pragma unroll
      for (int j = 0; j < 4; ++j) psum[j] += __shfl_xor(psum[j], mask, 64);
#pragma unroll
    for (int j = 0; j < 4; ++j) {
      lrow[j] = lrow[j] * fac[j] + psum[j];
      mrow[j] = mnew[j];
    }
#pragma unroll
    for (int n = 0; n < 4; ++n)
#pragma unroll
      for (int j = 0; j < 4; ++j) o[n][j] *= fac[j];

    // PV: A = P (row = lane&15), B = V^T rows (dk)
    bf16x8 pf0 = *(const bf16x8*)&Pb[w][lr * 72 + lk * 8];
    bf16x8 pf1 = *(const bf16x8*)&Pb[w][lr * 72 + 32 + lk * 8];
#pragma unroll
    for (int n = 0; n < 4; ++n) {
      bf16x8 vf0 = *(const bf16x8*)&Vt[(n * 16 + lr) * 72 + lk * 8];
      bf16x8 vf1 = *(const bf16x8*)&Vt[(n * 16 + lr) * 72 + 32 + lk * 8];
      o[n] = __builtin_amdgcn_mfma_f32_16x16x32_bf16(pf0, vf0, o[n], 0, 0, 0);
      o[n] = __builtin_amdgcn_mfma_f32_16x16x32_bf16(pf1, vf1, o[n], 0, 0, 0);
    }
  }

  // epilogue: ctx[b, s, h*64+dk]
  const int bb = bh >> 4, h = bh & 15;
#pragma unroll
  for (int n = 0; n < 4; ++n)
#pragma unroll
    for (int j = 0; j < 4; ++j) {
      int s = s0 + w * 16 + lk * 4 + j;
      int dk = n * 16 + lr;
      float v = o[n][j] / lrow[j];
      ctx[((long)(bb * S_ + s) * D_) + h * 64 + dk] = f2bf(v);
    }
}

// ---------------- out = residual + LayerNorm(a) ----------------
template <int RES_BF16, int OUT_BF16>
__global__ __launch_bounds__(256)
void add_ln(const void* __restrict__ resv, const short* __restrict__ a,
            const float* __restrict__ gam, const float* __restrict__ bet,
            void* __restrict__ outv) {
  const int row = blockIdx.x, t = threadIdx.x;
  const int w = t >> 6, l = t & 63;
  const long roff = (long)row * D_;
  const int c = t * 4;
  s16x4 av = *(const s16x4*)(a + roff + c);
  float v0 = bf2f(av[0]), v1 = bf2f(av[1]), v2 = bf2f(av[2]), v3 = bf2f(av[3]);
  float s = v0 + v1 + v2 + v3;
#pragma unroll
  for (int mask = 1; mask < 64; mask <<= 1) s += __shfl_xor(s, mask, 64);
  __shared__ float r1[4], r2[4];
  if (l == 0) r1[w] = s;
  __syncthreads();
  float mu = (r1[0] + r1[1] + r1[2] + r1[3]) * (1.0f / D_);
  float d0 = v0 - mu, d1 = v1 - mu, d2 = v2 - mu, d3 = v3 - mu;
  float sq = d0 * d0 + d1 * d1 + d2 * d2 + d3 * d3;
#pragma unroll
  for (int mask = 1; mask < 64; mask <<= 1) sq += __shfl_xor(sq, mask, 64);
  if (l == 0) r2[w] = sq;
  __syncthreads();
  float var = (r2[0] + r2[1] + r2[2] + r2[3]) * (1.0f / D_);
  float rs = rsqrtf(var + 1e-5f);
  float res0, res1, res2, res3;
  if (RES_BF16) {
    s16x4 rv = *(const s16x4*)((const short*)resv + roff + c);
    res0 = bf2f(rv[0]); res1 = bf2f(rv[1]); res2 = bf2f(rv[2]); res3 = bf2f(rv[3]);
  } else {
    f32x4 rv = *(const f32x4*)((const float*)resv + roff + c);
    res0 = rv[0]; res1 = rv[1]; res2 = rv[2]; res3 = rv[3];
  }
  float o0 = res0 + d0 * rs * gam[c + 0] + bet[c + 0];
  float o1 = res1 + d1 * rs * gam[c + 1] + bet[c + 1];
  float o2 = res2 + d2 * rs * gam[c + 2] + bet[c + 2];
  float o3 = res3 + d3 * rs * gam[c + 3] + bet[c + 3];
  if (OUT_BF16) {
    s16x4 ov;
    ov[0] = f2bf(o0); ov[1] = f2bf(o1); ov[2] = f2bf(o2); ov[3] = f2bf(o3);
    *(s16x4*)((short*)outv + roff + c) = ov;
  } else {
    f32x4 ov;
    ov[0] = o0; ov[1] = o1; ov[2] = o2; ov[3] = o3;
    *(f32x4*)((float*)outv + roff + c) = ov;
  }
}

extern "C" void kernel_launch(void* const* d_in, const int* in_sizes, int n_in,
                              void* d_out, int out_size, void* d_ws, size_t ws_size,
                              hipStream_t stream) {
  (void)in_sizes; (void)n_in; (void)out_size; (void)ws_size;
  const float* x   = (const float*)d_in[0];
  const float* wq  = (const float*)d_in[1];
  const float* bq  = (const float*)d_in[2];
  const float* wk  = (const float*)d_in[3];
  const float* bk  = (const float*)d_in[4];
  const float* wv  = (const float*)d_in[5];
  const float* bv  = (const float*)d_in[6];
  const float* wo  = (const float*)d_in[7];
  const float* bo  = (const float*)d_in[8];
  const float* w1  = (const float*)d_in[9];
  const float* b1  = (const float*)d_in[10];
  const float* w2  = (const float*)d_in[11];
  const float* b2  = (const float*)d_in[12];
  const float* g1  = (const float*)d_in[13];
  const float* be1 = (const float*)d_in[14];
  const float* g2  = (const float*)d_in[15];
  const float* be2 = (const float*)d_in[16];

  char* ws = (char*)d_ws;
  const long MB = 1 << 20;
  short* xb    = (short*)(ws + 0 * MB);
  short* wqkvb = (short*)(ws + 16 * MB);
  short* wob   = (short*)(ws + 22 * MB);
  short* w1b   = (short*)(ws + 24 * MB);
  short* w2b   = (short*)(ws + 32 * MB);
  short* Qb    = (short*)(ws + 40 * MB);
  short* Kb    = (short*)(ws + 56 * MB);
  short* Vb    = (short*)(ws + 72 * MB);
  short* ctxb  = (short*)(ws + 88 * MB);
  short* aout  = (short*)(ws + 40 * MB);   // reuse Q
  short* x1b   = (short*)(ws + 56 * MB);   // reuse K
  short* hid   = (short*)(ws + 88 * MB);   // reuse ctx.. (64MB, [88,152))
  short* ffb   = (short*)(ws + 72 * MB);   // reuse V

  auto cvt = [&](const float* in, short* out, long n) {
    cvt_kernel<<<dim3((unsigned)((n / 8 + 255) / 256)), dim3(256), 0, stream>>>(in, out, (int)n);
  };
  cvt(x, xb, (long)M_ * D_);
  cvt(wq, wqkvb + 0L * D_ * D_, (long)D_ * D_);
  cvt(wk, wqkvb + 1L * D_ * D_, (long)D_ * D_);
  cvt(wv, wqkvb + 2L * D_ * D_, (long)D_ * D_);
  cvt(wo, wob, (long)D_ * D_);
  cvt(w1, w1b, (long)DFF_ * D_);
  cvt(w2, w2b, (long)D_ * DFF_);

  // QKV projection (fused, N=3072) with scatter to [B,H,S,DK]
  gemm_bt<2><<<dim3(3072 / 128, M_ / 128), 256, 0, stream>>>(
      xb, wqkvb, bq, bk, bv, nullptr, M_, 3072, D_, Qb, Kb, Vb);

  attn_kernel<<<dim3(S_ / 64, B_ * H_), 256, 0, stream>>>(Qb, Kb, Vb, ctxb);

  // O projection
  gemm_bt<0><<<dim3(D_ / 128, M_ / 128), 256, 0, stream>>>(
      ctxb, wob, bo, nullptr, nullptr, aout, M_, D_, D_, nullptr, nullptr, nullptr);

  // x1 = x + LN(attn_out)
  add_ln<0, 1><<<dim3(M_), 256, 0, stream>>>(x, aout, g1, be1, x1b);

  // FFN
  gemm_bt<1><<<dim3(DFF_ / 128, M_ / 128), 256, 0, stream>>>(
      x1b, w1b, b1, nullptr, nullptr, hid, M_, DFF_, D_, nullptr, nullptr, nullptr);
  gemm_bt<0><<<dim3(D_ / 128, M_ / 128), 256, 0, stream>>>(
      hid, w2b, b2, nullptr, nullptr, ffb, M_, D_, DFF_, nullptr, nullptr, nullptr);

  // out = x1 + LN(ff)
  add_ln<1, 0><<<dim3(M_), 256, 0, stream>>>(x1b, ffb, g2, be2, d_out);
}

// Round 3
// 432.299 us; speedup vs baseline: 1.3276x; 1.3276x over previous
//
#include <hip/hip_runtime.h>
#include <hip/hip_bf16.h>
#include <stdint.h>

// EncoderBlock on MI355X (gfx950), bf16 MFMA pipeline.
// B=4 S=2048 D=1024 H=16 DK=64 DFF=4096.
// Attention: m214-style swapped-QK^T 32x32 structure, V^T staged from global,
// in-register softmax + cvt_pk/permlane32_swap P redistribution.

#define DI __device__ __forceinline__

typedef __attribute__((ext_vector_type(4))) float f32x4;
typedef __attribute__((ext_vector_type(16))) float f32x16;
typedef __attribute__((ext_vector_type(8))) short bf16x8;
typedef __attribute__((ext_vector_type(4))) short s16x4;

#define B_ 4
#define S_ 2048
#define D_ 1024
#define H_ 16
#define DK_ 64
#define DFF_ 4096
#define M_ 8192

DI float bf2f(short s) {
  union { unsigned u; float f; } v;
  v.u = ((unsigned)(unsigned short)s) << 16;
  return v.f;
}
DI short f2bf(float f) {
  union { float f; unsigned u; } v;
  v.f = f;
  unsigned r = v.u + 0x7FFFu + ((v.u >> 16) & 1u);
  return (short)(r >> 16);
}
DI unsigned pkbf(float lo, float hi) {
  unsigned r;
  asm("v_cvt_pk_bf16_f32 %0, %1, %2" : "=v"(r) : "v"(lo), "v"(hi));
  return r;
}
DI void plswap(unsigned& a, unsigned& b) {
  asm volatile("v_permlane32_swap_b32 %0, %1" : "+v"(a), "+v"(b));
}

// ---------------- fp32 -> bf16 convert (vectorized) ----------------
__global__ __launch_bounds__(256) void cvt_kernel(const float* __restrict__ in,
                                                  short* __restrict__ out, int n) {
  long i = ((long)blockIdx.x * blockDim.x + threadIdx.x) * 8;
  if (i >= n) return;
  f32x4 a = *(const f32x4*)(in + i);
  f32x4 b = *(const f32x4*)(in + i + 4);
  bf16x8 r;
  r[0] = f2bf(a[0]); r[1] = f2bf(a[1]); r[2] = f2bf(a[2]); r[3] = f2bf(a[3]);
  r[4] = f2bf(b[0]); r[5] = f2bf(b[1]); r[6] = f2bf(b[2]); r[7] = f2bf(b[3]);
  *(bf16x8*)(out + i) = r;
}

// ---------------- GEMM C = A @ B^T (+bias, epilogue variants) ----------------
DI void gl_lds16(const void* g, void* l) {
  __builtin_amdgcn_global_load_lds(
      (const __attribute__((address_space(1))) unsigned int*)g,
      (__attribute__((address_space(3))) unsigned int*)l, 16, 0, 0);
}

// MODE 0: bf16 out + bias; MODE 1: + ReLU; MODE 2: QKV scatter (Q scaled 1/8,
//   Q/K -> [B,H,S,DK], V -> transposed [B,H,DK,S])
template <int MODE>
__global__ __launch_bounds__(256, 2)
void gemm_bt(const short* __restrict__ A, const short* __restrict__ Bm,
             const float* __restrict__ bias0, const float* __restrict__ bias1,
             const float* __restrict__ bias2, short* __restrict__ C,
             int M, int N, int K,
             short* __restrict__ Qo, short* __restrict__ Ko, short* __restrict__ Vo) {
  __shared__ short As[128 * 32];
  __shared__ short Bs[128 * 32];
  const int t = threadIdx.x, w = t >> 6, l = t & 63;
  const int row0 = blockIdx.y * 128, col0 = blockIdx.x * 128;
  const int wr = (w >> 1) * 64, wc = (w & 1) * 64;
  const int lr = l & 15, lk = l >> 4;

  f32x4 acc[4][4] = {};

  const int e0 = (w * 64 + l) * 8;
  const int e1 = ((4 + w) * 64 + l) * 8;
  const int ar0 = e0 >> 5, ac0 = e0 & 31;
  const int ar1 = e1 >> 5, ac1 = e1 & 31;
  short* la0 = &As[w * 512];
  short* la1 = &As[(4 + w) * 512];
  short* lb0 = &Bs[w * 512];
  short* lb1 = &Bs[(4 + w) * 512];
  const short* Ab = A + (long)row0 * K;
  const short* Bb = Bm + (long)col0 * K;

  for (int k0 = 0; k0 < K; k0 += 32) {
    __syncthreads();
    gl_lds16(Ab + (long)ar0 * K + k0 + ac0, la0);
    gl_lds16(Ab + (long)ar1 * K + k0 + ac1, la1);
    gl_lds16(Bb + (long)ar0 * K + k0 + ac0, lb0);
    gl_lds16(Bb + (long)ar1 * K + k0 + ac1, lb1);
    __syncthreads();
    bf16x8 af[4], bfr[4];
#pragma unroll
    for (int m = 0; m < 4; ++m)
      af[m] = *(const bf16x8*)&As[(wr + m * 16 + lr) * 32 + lk * 8];
#pragma unroll
    for (int n = 0; n < 4; ++n)
      bfr[n] = *(const bf16x8*)&Bs[(wc + n * 16 + lr) * 32 + lk * 8];
#pragma unroll
    for (int m = 0; m < 4; ++m)
#pragma unroll
      for (int n = 0; n < 4; ++n)
        acc[m][n] =
            __builtin_amdgcn_mfma_f32_16x16x32_bf16(af[m], bfr[n], acc[m][n], 0, 0, 0);
  }

  // epilogue: C/D layout col = lane&15, row = (lane>>4)*4 + j
  if (MODE == 2) {
    const int which = col0 >> 10;  // uniform per block (128 | 1024)
#pragma unroll
    for (int m = 0; m < 4; ++m) {
#pragma unroll
      for (int n = 0; n < 4; ++n) {
        const int r0 = row0 + wr + m * 16 + lk * 4;
        const int c = col0 + wc + n * 16 + lr;
        const int cc = c & 1023;
        const int h = cc >> 6, dk = cc & 63;
        const int bb = r0 >> 11, s = r0 & 2047;
        if (which == 2) {
          const float bias = bias2[cc];
          s16x4 v4;
#pragma unroll
          for (int j = 0; j < 4; ++j) v4[j] = f2bf(acc[m][n][j] + bias);
          *(s16x4*)(Vo + ((long)((bb * H_ + h) * DK_ + dk)) * S_ + s) = v4;
        } else {
          const float bias = (which == 0 ? bias0[cc] : bias1[cc]);
          const float sc = (which == 0 ? 0.125f : 1.0f);
          short* dst = (which == 0 ? Qo : Ko);
#pragma unroll
          for (int j = 0; j < 4; ++j)
            dst[(((long)(bb * H_ + h) * S_) + s + j) * DK_ + dk] =
                f2bf((acc[m][n][j] + bias) * sc);
        }
      }
    }
  } else {
#pragma unroll
    for (int m = 0; m < 4; ++m) {
#pragma unroll
      for (int n = 0; n < 4; ++n) {
#pragma unroll
        for (int j = 0; j < 4; ++j) {
          int r = row0 + wr + m * 16 + lk * 4 + j;
          int c = col0 + wc + n * 16 + lr;
          float v = acc[m][n][j] + bias0[c];
          if (MODE == 1) v = fmaxf(v, 0.0f);
          C[(long)r * N + c] = f2bf(v);
        }
      }
    }
  }
}

// ---------------- Flash attention, swapped-QK^T 32x32 structure ----------------
// 4 warps x 32 q-rows = 128 q/block.  KV tile 64.  K tile [64kv][64dk] and
// V^T tile [64dk][64kv] staged linear in LDS via global_load_lds with
// pre-swizzled source (slot ^= row&7); reads XOR-unswizzle.
__global__ __launch_bounds__(256, 3)
void attn_kernel(const short* __restrict__ Q, const short* __restrict__ K,
                 const short* __restrict__ Vt, short* __restrict__ ctx) {
  __shared__ short Ks[64 * 64];
  __shared__ short Vs[64 * 64];
  const int t = threadIdx.x, w = t >> 6, l = t & 63;
  const int q31 = l & 31, hi = l >> 5;
  const int bh = blockIdx.y;
  const int q0 = blockIdx.x * 128 + w * 32;
  const long base = (long)bh * S_ * DK_;

  // Q fragments (prescaled by 1/8 in QKV GEMM).  B-frag: col=l&31, k=hi*8+e.
  bf16x8 qf[4];
  {
    const short* qp = Q + base + (long)(q0 + q31) * DK_ + hi * 8;
#pragma unroll
    for (int ks = 0; ks < 4; ++ks) qf[ks] = *(const bf16x8*)(qp + ks * 16);
  }

  f32x16 oa[2] = {};  // O^T: [mt] dk=32mt+crow(r,hi), q=l&31
  float mrun = -1e30f, lrun = 0.0f;

  const int srow = l >> 3;                 // 0..7 within 8-row chunk
  const int scol = ((l & 7) ^ srow) * 8;   // swizzled source col (shorts)
  short* ldsK0 = &Ks[w * 1024];
  short* ldsK1 = &Ks[w * 1024 + 512];
  short* ldsV0 = &Vs[w * 1024];
  short* ldsV1 = &Vs[w * 1024 + 512];
  const int kr0 = w * 16 + srow, kr1 = w * 16 + 8 + srow;

  for (int kv0 = 0; kv0 < S_; kv0 += 64) {
    __syncthreads();
    gl_lds16(K + base + (long)(kv0 + kr0) * DK_ + scol, ldsK0);
    gl_lds16(K + base + (long)(kv0 + kr1) * DK_ + scol, ldsK1);
    gl_lds16(Vt + base + (long)kr0 * S_ + kv0 + scol, ldsV0);
    gl_lds16(Vt + base + (long)kr1 * S_ + kv0 + scol, ldsV1);
    __syncthreads();

    // S^T = K x Q: D[kv][q], col=q=l&31, row=crow(r,hi)
    f32x16 sacc[2] = {};
#pragma unroll
    for (int m = 0; m < 2; ++m) {
      const int row = m * 32 + q31;
      const int sw = row & 7;
#pragma unroll
      for (int ks = 0; ks < 4; ++ks) {
        bf16x8 kf = *(const bf16x8*)&Ks[row * 64 + (((2 * ks + hi) ^ sw) << 3)];
        sacc[m] = __builtin_amdgcn_mfma_f32_32x32x16_bf16(kf, qf[ks], sacc[m], 0, 0, 0);
      }
    }

    // online softmax (lane-local row q; partner lane holds other 32 kv)
    float tm = sacc[0][0];
#pragma unroll
    for (int r = 1; r < 16; ++r) tm = fmaxf(tm, sacc[0][r]);
#pragma unroll
    for (int r = 0; r < 16; ++r) tm = fmaxf(tm, sacc[1][r]);
    tm = fmaxf(tm, __shfl_xor(tm, 32, 64));
    const float mnew = fmaxf(mrun, tm);
    const float fac = __expf(mrun - mnew);
    float ps = 0.0f;
#pragma unroll
    for (int m = 0; m < 2; ++m)
#pragma unroll
      for (int r = 0; r < 16; ++r) {
        float p = __expf(sacc[m][r] - mnew);
        sacc[m][r] = p;
        ps += p;
      }
    ps += __shfl_xor(ps, 32, 64);
    lrun = lrun * fac + ps;
    mrun = mnew;
#pragma unroll
    for (int m = 0; m < 2; ++m)
#pragma unroll
      for (int r = 0; r < 16; ++r) oa[m][r] *= fac;

    // P -> bf16 B-frags: frag(s=2m+sb); words via cvt_pk + permlane32_swap
    bf16x8 pf[4];
#pragma unroll
    for (int m = 0; m < 2; ++m)
#pragma unroll
      for (int sb = 0; sb < 2; ++sb) {
        unsigned p0 = pkbf(sacc[m][8 * sb + 0], sacc[m][8 * sb + 1]);
        unsigned p1 = pkbf(sacc[m][8 * sb + 2], sacc[m][8 * sb + 3]);
        unsigned p2 = pkbf(sacc[m][8 * sb + 4], sacc[m][8 * sb + 5]);
        unsigned p3 = pkbf(sacc[m][8 * sb + 6], sacc[m][8 * sb + 7]);
        plswap(p0, p2);  // p0 -> word0, p2 -> word2
        plswap(p1, p3);  // p1 -> word1, p3 -> word3
        union { unsigned u[4]; bf16x8 v; } fb;
        fb.u[0] = p0; fb.u[1] = p1; fb.u[2] = p2; fb.u[3] = p3;
        pf[2 * m + sb] = fb.v;
      }

    // O^T += V^T x P : D[dk][q]
#pragma unroll
    for (int mt = 0; mt < 2; ++mt) {
      const int row = mt * 32 + q31;
      const int sw = row & 7;
#pragma unroll
      for (int s = 0; s < 4; ++s) {
        bf16x8 vf = *(const bf16x8*)&Vs[row * 64 + (((2 * s + hi) ^ sw) << 3)];
        oa[mt] = __builtin_amdgcn_mfma_f32_32x32x16_bf16(vf, pf[s], oa[mt], 0, 0, 0);
      }
    }
  }

  // epilogue: ctx[b, s=q0+q31, h*64+dk], dk = 32mt+8g+4hi+i (i=0..3 packed)
  const int bb2 = bh >> 4, h = bh & 15;
  const float rl = 1.0f / lrun;
  short* crow = ctx + ((long)(bb2 * S_ + q0 + q31)) * D_ + h * 64 + 4 * hi;
#pragma unroll
  for (int mt = 0; mt < 2; ++mt)
#pragma unroll
    for (int g = 0; g < 4; ++g) {
      s16x4 v4;
#pragma unroll
      for (int i = 0; i < 4; ++i) v4[i] = f2bf(oa[mt][4 * g + i] * rl);
      *(s16x4*)(crow + mt * 32 + g * 8) = v4;
    }
}

// ---------------- out = residual + LayerNorm(a) ----------------
template <int RES_BF16, int OUT_BF16>
__global__ __launch_bounds__(256)
void add_ln(const void* __restrict__ resv, const short* __restrict__ a,
            const float* __restrict__ gam, const float* __restrict__ bet,
            void* __restrict__ outv) {
  const int row = blockIdx.x, t = threadIdx.x;
  const int w = t >> 6, l = t & 63;
  const long roff = (long)row * D_;
  const int c = t * 4;
  s16x4 av = *(const s16x4*)(a + roff + c);
  float v0 = bf2f(av[0]), v1 = bf2f(av[1]), v2 = bf2f(av[2]), v3 = bf2f(av[3]);
  float s = v0 + v1 + v2 + v3;
#pragma unroll
  for (int mask = 1; mask < 64; mask <<= 1) s += __shfl_xor(s, mask, 64);
  __shared__ float r1[4], r2[4];
  if (l == 0) r1[w] = s;
  __syncthreads();
  float mu = (r1[0] + r1[1] + r1[2] + r1[3]) * (1.0f / D_);
  float d0 = v0 - mu, d1 = v1 - mu, d2 = v2 - mu, d3 = v3 - mu;
  float sq = d0 * d0 + d1 * d1 + d2 * d2 + d3 * d3;
#pragma unroll
  for (int mask = 1; mask < 64; mask <<= 1) sq += __shfl_xor(sq, mask, 64);
  if (l == 0) r2[w] = sq;
  __syncthreads();
  float var = (r2[0] + r2[1] + r2[2] + r2[3]) * (1.0f / D_);
  float rs = rsqrtf(var + 1e-5f);
  float res0, res1, res2, res3;
  if (RES_BF16) {
    s16x4 rv = *(const s16x4*)((const short*)resv + roff + c);
    res0 = bf2f(rv[0]); res1 = bf2f(rv[1]); res2 = bf2f(rv[2]); res3 = bf2f(rv[3]);
  } else {
    f32x4 rv = *(const f32x4*)((const float*)resv + roff + c);
    res0 = rv[0]; res1 = rv[1]; res2 = rv[2]; res3 = rv[3];
  }
  float o0 = res0 + d0 * rs * gam[c + 0] + bet[c + 0];
  float o1 = res1 + d1 * rs * gam[c + 1] + bet[c + 1];
  float o2 = res2 + d2 * rs * gam[c + 2] + bet[c + 2];
  float o3 = res3 + d3 * rs * gam[c + 3] + bet[c + 3];
  if (OUT_BF16) {
    s16x4 ov;
    ov[0] = f2bf(o0); ov[1] = f2bf(o1); ov[2] = f2bf(o2); ov[3] = f2bf(o3);
    *(s16x4*)((short*)outv + roff + c) = ov;
  } else {
    f32x4 ov;
    ov[0] = o0; ov[1] = o1; ov[2] = o2; ov[3] = o3;
    *(f32x4*)((float*)outv + roff + c) = ov;
  }
}

extern "C" void kernel_launch(void* const* d_in, const int* in_sizes, int n_in,
                              void* d_out, int out_size, void* d_ws, size_t ws_size,
                              hipStream_t stream) {
  (void)in_sizes; (void)n_in; (void)out_size; (void)ws_size;
  const float* x   = (const float*)d_in[0];
  const float* wq  = (const float*)d_in[1];
  const float* bq  = (const float*)d_in[2];
  const float* wk  = (const float*)d_in[3];
  const float* bk  = (const float*)d_in[4];
  const float* wv  = (const float*)d_in[5];
  const float* bv  = (const float*)d_in[6];
  const float* wo  = (const float*)d_in[7];
  const float* bo  = (const float*)d_in[8];
  const float* w1  = (const float*)d_in[9];
  const float* b1  = (const float*)d_in[10];
  const float* w2  = (const float*)d_in[11];
  const float* b2  = (const float*)d_in[12];
  const float* g1  = (const float*)d_in[13];
  const float* be1 = (const float*)d_in[14];
  const float* g2  = (const float*)d_in[15];
  const float* be2 = (const float*)d_in[16];

  char* ws = (char*)d_ws;
  const long MB = 1 << 20;
  short* xb    = (short*)(ws + 0 * MB);
  short* wqkvb = (short*)(ws + 16 * MB);
  short* wob   = (short*)(ws + 22 * MB);
  short* w1b   = (short*)(ws + 24 * MB);
  short* w2b   = (short*)(ws + 32 * MB);
  short* Qb    = (short*)(ws + 40 * MB);
  short* Kb    = (short*)(ws + 56 * MB);
  short* Vtb   = (short*)(ws + 72 * MB);   // V transposed [B,H,DK,S]
  short* ctxb  = (short*)(ws + 88 * MB);
  short* aout  = (short*)(ws + 40 * MB);   // reuse Q
  short* x1b   = (short*)(ws + 56 * MB);   // reuse K
  short* hid   = (short*)(ws + 88 * MB);   // reuse ctx (64MB, [88,152))
  short* ffb   = (short*)(ws + 72 * MB);   // reuse Vt

  auto cvt = [&](const float* in, short* out, long n) {
    cvt_kernel<<<dim3((unsigned)((n / 8 + 255) / 256)), dim3(256), 0, stream>>>(in, out, (int)n);
  };
  cvt(x, xb, (long)M_ * D_);
  cvt(wq, wqkvb + 0L * D_ * D_, (long)D_ * D_);
  cvt(wk, wqkvb + 1L * D_ * D_, (long)D_ * D_);
  cvt(wv, wqkvb + 2L * D_ * D_, (long)D_ * D_);
  cvt(wo, wob, (long)D_ * D_);
  cvt(w1, w1b, (long)DFF_ * D_);
  cvt(w2, w2b, (long)D_ * DFF_);

  // QKV projection (fused, N=3072): Q scaled 1/8, V written transposed
  gemm_bt<2><<<dim3(3072 / 128, M_ / 128), 256, 0, stream>>>(
      xb, wqkvb, bq, bk, bv, nullptr, M_, 3072, D_, Qb, Kb, Vtb);

  attn_kernel<<<dim3(S_ / 128, B_ * H_), 256, 0, stream>>>(Qb, Kb, Vtb, ctxb);

  // O projection
  gemm_bt<0><<<dim3(D_ / 128, M_ / 128), 256, 0, stream>>>(
      ctxb, wob, bo, nullptr, nullptr, aout, M_, D_, D_, nullptr, nullptr, nullptr);

  // x1 = x + LN(attn_out)
  add_ln<0, 1><<<dim3(M_), 256, 0, stream>>>(x, aout, g1, be1, x1b);

  // FFN
  gemm_bt<1><<<dim3(DFF_ / 128, M_ / 128), 256, 0, stream>>>(
      x1b, w1b, b1, nullptr, nullptr, hid, M_, DFF_, D_, nullptr, nullptr, nullptr);
  gemm_bt<0><<<dim3(D_ / 128, M_ / 128), 256, 0, stream>>>(
      hid, w2b, b2, nullptr, nullptr, ffb, M_, D_, DFF_, nullptr, nullptr, nullptr);

  // out = x1 + LN(ff)
  add_ln<1, 0><<<dim3(M_), 256, 0, stream>>>(x1b, ffb, g2, be2, d_out);
}